// Round 2
// baseline (157.342 us; speedup 1.0000x reference)
//
#include <hip/hip_runtime.h>

// Problem constants (from reference)
#define BS 2
#define NF 16
#define CH 32
#define HH 128
#define WW 128
#define HW (HH * WW)   // 16384
#define NM 8           // NUM_MASKS
#define NK 3           // NUM_CLASSES
#define MID (NF / 2)   // 8

#define S 64           // spatial px per block
#define FSPLIT 2       // frame halves across blocks
#define FPB (NF / FSPLIT)  // 8 frames per block

// ---------------------------------------------------------------------------
// Fused kernel: per block (b, fh, chunk of 64 px):
//   1. stage dec[b,MID,:,chunk] into LDS (8 KB)
//   2. compute masks[b,:,chunk] from it (write to global once, keep in LDS)
//   3. f-loop over 8 frames: acc[m] += dec[b,f,c,px] * mask[m,px]
//   4. shuffle-reduce over 16 spatial lanes, atomicAdd into acc_ws[b,m,c]
// Grid: 2*2*256 = 1024 blocks x 256 thr -> 4 blocks/CU, 16 waves/CU (50%).
// Masks are loop-invariant over f -> compiler hoists 8 float4 into regs:
// only 8 ds_read_b128 per thread for the whole f-loop.
// ---------------------------------------------------------------------------
__global__ __launch_bounds__(256) void fused_kernel(
    const float* __restrict__ dec, const float* __restrict__ seg_w,
    const float* __restrict__ seg_b, float* __restrict__ masks_out,
    float* __restrict__ acc_ws) {
  __shared__ float mid[CH][S];  // 8 KB
  __shared__ float msk[NM][S];  // 2 KB

  int t = threadIdx.x;
  int bid = blockIdx.x;          // 0..1023
  int b = bid >> 9;
  int fh = (bid >> 8) & 1;
  int chunk = bid & 255;
  int cs = chunk * S;

  // --- 1. stage mid-frame chunk: 32 rows x 64 px = 512 float4, 2/thread ---
  const float* midg = dec + (size_t)(b * NF + MID) * CH * HW + cs;
  {
    int col = t & 15, row = t >> 4;  // 16 float4 per row, rows 0..15 then 16..31
    *(float4*)&mid[row][col * 4] =
        *(const float4*)(midg + (size_t)row * HW + col * 4);
    *(float4*)&mid[row + 16][col * 4] =
        *(const float4*)(midg + (size_t)(row + 16) * HW + col * 4);
  }
  __syncthreads();

  // --- 2. masks: 8 m x 64 px = 512 values, 2/thread. m is wave-uniform ---
  float* mout = masks_out + (size_t)b * NM * HW + cs;
#pragma unroll
  for (int i = 0; i < 2; ++i) {
    int idx = t + 256 * i;
    int m = idx >> 6, px = idx & 63;
    float v = seg_b[m];
#pragma unroll
    for (int c = 0; c < CH; ++c) v += mid[c][px] * seg_w[m * CH + c];
    msk[m][px] = v;
    if (fh == 0) mout[(size_t)m * HW + px] = v;  // write masks output once
  }
  __syncthreads();

  // --- 3. pool: thread = (cg, cg+16) channels x s-lane, 8 frames ---
  int s = t & 15;   // 16 lanes x float4 = 64 px
  int cg = t >> 4;  // channel group 0..15 -> channels cg, cg+16

  const float* base =
      dec + (size_t)(b * NF + fh * FPB) * CH * HW + cs + s * 4;

  float acc0[NM], acc1[NM];
#pragma unroll
  for (int m = 0; m < NM; ++m) { acc0[m] = 0.f; acc1[m] = 0.f; }

#pragma unroll
  for (int f = 0; f < FPB; ++f) {
    float4 x0 = *(const float4*)(base + ((size_t)f * CH + cg) * HW);
    float4 x1 = *(const float4*)(base + ((size_t)f * CH + cg + 16) * HW);
#pragma unroll
    for (int m = 0; m < NM; ++m) {
      float4 w = *(const float4*)&msk[m][s * 4];  // f-invariant -> hoisted
      acc0[m] += x0.x * w.x + x0.y * w.y + x0.z * w.z + x0.w * w.w;
      acc1[m] += x1.x * w.x + x1.y * w.y + x1.z * w.z + x1.w * w.w;
    }
  }

  // --- 4. reduce across 16 spatial lanes, then atomics ---
#pragma unroll
  for (int off = 8; off >= 1; off >>= 1) {
#pragma unroll
    for (int m = 0; m < NM; ++m) {
      acc0[m] += __shfl_down(acc0[m], off, 16);
      acc1[m] += __shfl_down(acc1[m], off, 16);
    }
  }
  if (s == 0) {
#pragma unroll
    for (int m = 0; m < NM; ++m) {
      atomicAdd(&acc_ws[(b * NM + m) * CH + cg], acc0[m]);
      atomicAdd(&acc_ws[(b * NM + m) * CH + cg + 16], acc1[m]);
    }
  }
}

// ---------------------------------------------------------------------------
// Head: logits[b, m*NK+k] = (acc_ws[b,m,:]/NF) . logits_w[k,:] + logits_b[k]
// ---------------------------------------------------------------------------
__global__ __launch_bounds__(64) void head_kernel(
    const float* __restrict__ acc_ws, const float* __restrict__ lw,
    const float* __restrict__ lb, float* __restrict__ out) {
  int t = threadIdx.x;
  if (t < BS * NM * NK) {
    int b = t / (NM * NK);
    int r = t % (NM * NK);
    int m = r / NK;
    int k = r % NK;
    float ssum = 0.f;
#pragma unroll
    for (int c = 0; c < CH; ++c)
      ssum += acc_ws[(b * NM + m) * CH + c] * lw[k * CH + c];
    out[t] = ssum * (1.0f / NF) + lb[k];
  }
}

extern "C" void kernel_launch(void* const* d_in, const int* in_sizes, int n_in,
                              void* d_out, int out_size, void* d_ws,
                              size_t ws_size, hipStream_t stream) {
  const float* dec = (const float*)d_in[0];    // (2,16,32,128,128)
  const float* seg_w = (const float*)d_in[1];  // (8,32)
  const float* seg_b = (const float*)d_in[2];  // (8,)
  const float* lw = (const float*)d_in[3];     // (3,32)
  const float* lb = (const float*)d_in[4];     // (3,)

  float* out = (float*)d_out;
  float* logits_out = out;                // 48 floats
  float* masks_out = out + BS * NM * NK;  // 262144 floats, 192 B offset
  float* acc_ws = (float*)d_ws;           // 512 floats

  hipMemsetAsync(d_ws, 0, BS * NM * CH * sizeof(float), stream);

  fused_kernel<<<BS * FSPLIT * (HW / S), 256, 0, stream>>>(
      dec, seg_w, seg_b, masks_out, acc_ws);
  head_kernel<<<1, 64, 0, stream>>>(acc_ws, lw, lb, logits_out);
}

// Round 3
// 117.529 us; speedup vs baseline: 1.3388x; 1.3388x over previous
//
#include <hip/hip_runtime.h>

// Problem constants (from reference)
#define BS 2
#define NF 16
#define CH 32
#define HW 16384      // 128*128
#define NM 8          // NUM_MASKS
#define NK 3          // NUM_CLASSES
#define MID 8         // NF/2

#define S 64          // spatial px per block
#define FSPLIT 2      // frame halves across blocks
#define FPB (NF / FSPLIT)          // 8 frames per block
#define BPB (FSPLIT * (HW / S))    // blocks per batch = 512
#define NBLK (BS * BPB)            // 1024

// ---------------------------------------------------------------------------
// Fused kernel: per block (b, fh, chunk of 64 px):
//   0. issue all 16 pool float4 loads (latency hidden behind mask phase)
//   1. stage dec[b,MID,:,chunk] into LDS
//   2. compute masks[b,:,chunk] (write masks output from fh==0 blocks)
//   3. acc[m] += dec[b,f,c,px] * mask[m,px] over 8 frames
//   4. shuffle-reduce over 16 spatial lanes -> LDS -> ONE coalesced 1KB
//      partial write per block. NO ATOMICS (round-2 postmortem: serialized
//      same-address atomicAdd tail was ~all of the 74us).
// ---------------------------------------------------------------------------
__global__ __launch_bounds__(256, 4) void fused_kernel(
    const float* __restrict__ dec, const float* __restrict__ seg_w,
    const float* __restrict__ seg_b, float* __restrict__ masks_out,
    float* __restrict__ part) {
  __shared__ float mid[CH][S];    // 8 KB
  __shared__ float msk[NM][S];    // 2 KB
  __shared__ float pbuf[NM * CH]; // 1 KB

  int t = threadIdx.x;
  int bid = blockIdx.x;           // 0..1023
  int b = bid >> 9;
  int fh = (bid >> 8) & 1;
  int chunk = bid & 255;
  int cs = chunk * S;

  int s = t & 15;                 // spatial lane (16 x float4 = 64 px)
  int cg = t >> 4;                // channel group -> channels cg, cg+16

  // --- 0. issue all pool loads up front (independent of mask phase) ---
  const float* base =
      dec + (size_t)(b * NF + fh * FPB) * CH * HW + cs + s * 4;
  float4 x0[FPB], x1[FPB];
#pragma unroll
  for (int f = 0; f < FPB; ++f) {
    x0[f] = *(const float4*)(base + ((size_t)f * CH + cg) * HW);
    x1[f] = *(const float4*)(base + ((size_t)f * CH + cg + 16) * HW);
  }

  // --- 1. stage mid-frame chunk: 32 rows x 64 px, 2 float4/thread ---
  const float* midg = dec + (size_t)(b * NF + MID) * CH * HW + cs;
  {
    int col = t & 15, row = t >> 4;
    float4 a = *(const float4*)(midg + (size_t)row * HW + col * 4);
    float4 c2 = *(const float4*)(midg + (size_t)(row + 16) * HW + col * 4);
    *(float4*)&mid[row][col * 4] = a;
    *(float4*)&mid[row + 16][col * 4] = c2;
  }
  __syncthreads();

  // --- 2. masks: 8 m x 64 px, 2/thread; m wave-uniform, px stride-1 ---
  float* mout = masks_out + (size_t)b * NM * HW + cs;
#pragma unroll
  for (int i = 0; i < 2; ++i) {
    int idx = t + 256 * i;
    int m = idx >> 6, px = idx & 63;
    float v = seg_b[m];
#pragma unroll
    for (int c = 0; c < CH; ++c) v += mid[c][px] * seg_w[m * CH + c];
    msk[m][px] = v;
    if (fh == 0) mout[(size_t)m * HW + px] = v;
  }
  __syncthreads();

  // --- 3. pool FMAs (loads already in registers) ---
  float acc0[NM], acc1[NM];
#pragma unroll
  for (int m = 0; m < NM; ++m) { acc0[m] = 0.f; acc1[m] = 0.f; }

#pragma unroll
  for (int f = 0; f < FPB; ++f) {
#pragma unroll
    for (int m = 0; m < NM; ++m) {
      float4 w = *(const float4*)&msk[m][s * 4];  // compiler hoists what fits
      acc0[m] += x0[f].x * w.x + x0[f].y * w.y + x0[f].z * w.z + x0[f].w * w.w;
      acc1[m] += x1[f].x * w.x + x1[f].y * w.y + x1[f].z * w.z + x1[f].w * w.w;
    }
  }

  // --- 4. reduce across 16 spatial lanes, stage to LDS, coalesced write ---
#pragma unroll
  for (int off = 8; off >= 1; off >>= 1) {
#pragma unroll
    for (int m = 0; m < NM; ++m) {
      acc0[m] += __shfl_down(acc0[m], off, 16);
      acc1[m] += __shfl_down(acc1[m], off, 16);
    }
  }
  if (s == 0) {
#pragma unroll
    for (int m = 0; m < NM; ++m) {
      pbuf[m * CH + cg] = acc0[m];
      pbuf[m * CH + cg + 16] = acc1[m];
    }
  }
  __syncthreads();
  part[(size_t)bid * (NM * CH) + t] = pbuf[t];  // 1 KB, fully coalesced
}

// ---------------------------------------------------------------------------
// Reduce + head: one block per (b,m). Sums 512 partial rows, then computes
// the NK logits. Absorbs old head_kernel and the memset (no atomics left).
// ---------------------------------------------------------------------------
__global__ __launch_bounds__(256) void reduce_head_kernel(
    const float* __restrict__ part, const float* __restrict__ lw,
    const float* __restrict__ lb, float* __restrict__ out) {
  __shared__ float red[8][CH];
  __shared__ float pooled[CH];

  int t = threadIdx.x;
  int b = blockIdx.x >> 3;       // 0..1
  int m = blockIdx.x & 7;        // 0..7

  int c = t & 31, j = t >> 5;    // j: 8-way split over the 512 partials
  float sum = 0.f;
  const float* p = part + (size_t)b * BPB * (NM * CH) + m * CH + c;
  for (int i = j; i < BPB; i += 8)        // 64 iterations, coalesced in c
    sum += p[(size_t)i * (NM * CH)];
  red[j][c] = sum;
  __syncthreads();

  if (t < CH) {
    float v = 0.f;
#pragma unroll
    for (int jj = 0; jj < 8; ++jj) v += red[jj][t];
    pooled[t] = v * (1.0f / NF);
  }
  __syncthreads();

  if (t < NK) {
    float dot = 0.f;
#pragma unroll
    for (int cc = 0; cc < CH; ++cc) dot += pooled[cc] * lw[t * CH + cc];
    out[b * (NM * NK) + m * NK + t] = dot + lb[t];
  }
}

extern "C" void kernel_launch(void* const* d_in, const int* in_sizes, int n_in,
                              void* d_out, int out_size, void* d_ws,
                              size_t ws_size, hipStream_t stream) {
  const float* dec = (const float*)d_in[0];    // (2,16,32,128,128)
  const float* seg_w = (const float*)d_in[1];  // (8,32)
  const float* seg_b = (const float*)d_in[2];  // (8,)
  const float* lw = (const float*)d_in[3];     // (3,32)
  const float* lb = (const float*)d_in[4];     // (3,)

  float* out = (float*)d_out;
  float* logits_out = out;                // 48 floats
  float* masks_out = out + BS * NM * NK;  // 262144 floats, 192 B offset
  float* part = (float*)d_ws;             // 1024 x 256 floats = 1 MB

  fused_kernel<<<NBLK, 256, 0, stream>>>(dec, seg_w, seg_b, masks_out, part);
  reduce_head_kernel<<<BS * NM, 256, 0, stream>>>(part, lw, lb, logits_out);
}

// Round 4
// 106.780 us; speedup vs baseline: 1.4735x; 1.1007x over previous
//
#include <hip/hip_runtime.h>

// Problem constants (from reference)
#define BS 2
#define NF 16
#define CH 32
#define HW 16384      // 128*128
#define NM 8          // NUM_MASKS
#define NK 3          // NUM_CLASSES
#define MID 8         // NF/2

#define S 64          // spatial px per block
#define FSPLIT 2      // frame halves across blocks
#define FPB (NF / FSPLIT)          // 8 frames per block
#define BPB (FSPLIT * (HW / S))    // partial rows per batch = 512
#define NBLK (BS * BPB)            // 1024 blocks

// ---------------------------------------------------------------------------
// Fused kernel, round-4 restructure for occupancy:
//   512 threads/block, ONE channel per thread (c = t>>4, s = t&15).
//   Per-thread global traffic: 8 pool float4 + 1 mid float4 (was 16+2),
//   so VGPR fits under 64 -> __launch_bounds__(512,8) targets 4 blocks/CU
//   = 32 waves/CU (100%), vs 16 waves/CU in round 3 (latency-bound, all
//   pipes <10% busy). Mask fragments re-read from LDS per (m,f) instead of
//   hoisted: LDS traffic ~268 MB @ 69 TB/s ~ 4 us, not a bottleneck.
// ---------------------------------------------------------------------------
__global__ __launch_bounds__(512, 8) void fused_kernel(
    const float* __restrict__ dec, const float* __restrict__ seg_w,
    const float* __restrict__ seg_b, float* __restrict__ masks_out,
    float* __restrict__ part) {
  __shared__ float mid[CH][S];    // 8 KB
  __shared__ float msk[NM][S];    // 2 KB
  __shared__ float pbuf[NM * CH]; // 1 KB

  int t = threadIdx.x;
  int bid = blockIdx.x;           // 0..1023
  int b = bid >> 9;
  int fh = (bid >> 8) & 1;
  int chunk = bid & 255;
  int cs = chunk * S;

  int s = t & 15;                 // spatial lane (16 x float4 = 64 px)
  int c = t >> 4;                 // channel 0..31

  // --- 0. issue the 8 pool loads up front (hidden behind mask phase) ---
  const float* base =
      dec + (size_t)(b * NF + fh * FPB) * CH * HW + (size_t)c * HW + cs + s * 4;
  float4 x[FPB];
#pragma unroll
  for (int f = 0; f < FPB; ++f)
    x[f] = *(const float4*)(base + (size_t)f * CH * HW);

  // --- 1. stage mid-frame chunk: 1 float4/thread = 32 rows x 64 px ---
  {
    const float* midg = dec + (size_t)(b * NF + MID) * CH * HW + cs;
    *(float4*)&mid[c][s * 4] = *(const float4*)(midg + (size_t)c * HW + s * 4);
  }
  __syncthreads();

  // --- 2. masks: 512 values, 1/thread; m wave-uniform, px stride-1 ---
  {
    int m = t >> 6, px = t & 63;
    float v = seg_b[m];
#pragma unroll
    for (int cc = 0; cc < CH; ++cc) v += mid[cc][px] * seg_w[m * CH + cc];
    msk[m][px] = v;
    if (fh == 0)
      masks_out[(size_t)b * NM * HW + (size_t)m * HW + cs + px] = v;
  }
  __syncthreads();

  // --- 3. pool FMAs: m-outer keeps live mask fragment to one float4 ---
  float acc[NM];
#pragma unroll
  for (int m = 0; m < NM; ++m) {
    float4 w = *(const float4*)&msk[m][s * 4];
    float a = 0.f;
#pragma unroll
    for (int f = 0; f < FPB; ++f)
      a += x[f].x * w.x + x[f].y * w.y + x[f].z * w.z + x[f].w * w.w;
    acc[m] = a;
  }

  // --- 4. reduce across 16 spatial lanes -> LDS -> coalesced 1KB write ---
#pragma unroll
  for (int off = 8; off >= 1; off >>= 1)
#pragma unroll
    for (int m = 0; m < NM; ++m) acc[m] += __shfl_down(acc[m], off, 16);

  if (s == 0)
#pragma unroll
    for (int m = 0; m < NM; ++m) pbuf[m * CH + c] = acc[m];
  __syncthreads();
  if (t < NM * CH) part[(size_t)bid * (NM * CH) + t] = pbuf[t];
}

// ---------------------------------------------------------------------------
// Reduce + head: one block per (b,m), 1024 threads (32-way split over the
// 512 partial rows -> 16 strided loads/thread), then the NK-logit head.
// ---------------------------------------------------------------------------
__global__ __launch_bounds__(1024) void reduce_head_kernel(
    const float* __restrict__ part, const float* __restrict__ lw,
    const float* __restrict__ lb, float* __restrict__ out) {
  __shared__ float red[32][CH];   // 4 KB
  __shared__ float pooled[CH];

  int t = threadIdx.x;
  int b = blockIdx.x >> 3;        // 0..1
  int m = blockIdx.x & 7;         // 0..7

  int c = t & 31, j = t >> 5;     // j: 32-way split over 512 partials
  float sum = 0.f;
  const float* p = part + (size_t)b * BPB * (NM * CH) + m * CH + c;
  for (int i = j; i < BPB; i += 32)   // 16 iterations, coalesced in c
    sum += p[(size_t)i * (NM * CH)];
  red[j][c] = sum;
  __syncthreads();

  if (t < CH) {
    float v = 0.f;
#pragma unroll
    for (int jj = 0; jj < 32; ++jj) v += red[jj][t];
    pooled[t] = v * (1.0f / NF);
  }
  __syncthreads();

  if (t < NK) {
    float dot = 0.f;
#pragma unroll
    for (int cc = 0; cc < CH; ++cc) dot += pooled[cc] * lw[t * CH + cc];
    out[b * (NM * NK) + m * NK + t] = dot + lb[t];
  }
}

extern "C" void kernel_launch(void* const* d_in, const int* in_sizes, int n_in,
                              void* d_out, int out_size, void* d_ws,
                              size_t ws_size, hipStream_t stream) {
  const float* dec = (const float*)d_in[0];    // (2,16,32,128,128)
  const float* seg_w = (const float*)d_in[1];  // (8,32)
  const float* seg_b = (const float*)d_in[2];  // (8,)
  const float* lw = (const float*)d_in[3];     // (3,32)
  const float* lb = (const float*)d_in[4];     // (3,)

  float* out = (float*)d_out;
  float* logits_out = out;                // 48 floats
  float* masks_out = out + BS * NM * NK;  // 262144 floats, 192 B offset
  float* part = (float*)d_ws;             // 1024 x 256 floats = 1 MB

  fused_kernel<<<NBLK, 512, 0, stream>>>(dec, seg_w, seg_b, masks_out, part);
  reduce_head_kernel<<<BS * NM, 1024, 0, stream>>>(part, lw, lb, logits_out);
}